// Round 10
// baseline (65.193 us; speedup 1.0000x reference)
//
#include <hip/hip_runtime.h>
#include <hip/hip_bf16.h>

#define N_NODES 100000
#define HID 128
#define BB 64
#define CC 16
#define LL 256

typedef __bf16 b16x8 __attribute__((ext_vector_type(8)));
typedef float f32x4 __attribute__((ext_vector_type(4)));

__device__ __forceinline__ unsigned int bf16pair(float a, float b) {
  unsigned int ua = __float_as_uint(a), ub = __float_as_uint(b);
  ua = (ua + 0x7FFFu + ((ua >> 16) & 1u)) >> 16;
  ub = (ub + 0x7FFFu + ((ub >> 16) & 1u)) >> 16;
  return ua | (ub << 16);
}

__device__ __forceinline__ float elu(float v) {
  return v > 0.f ? v : (__expf(v) - 1.f);
}

// ---------------------------------------------------------------------------
// Prep: W_z [4][128][128] f32 -> bf16 fragment-linear layout.
// uint4 index u = ((kk*4 + ks)*8 + ot)*64 + lane
//   holds W_z[ks][o][h0..h0+7], o = ot*16 + (lane&15), h0 = kk*32 + (lane>>4)*8
// Chunk c = kk*4 + ks = 512 contiguous uint4 = 8KB.
// ---------------------------------------------------------------------------
__global__ void k_prep(const float* __restrict__ Wz, uint4* __restrict__ wfrag) {
  const int u = blockIdx.x * 256 + threadIdx.x;  // 8192 total
  const int lane = u & 63;
  const int ot = (u >> 6) & 7;
  const int ks = (u >> 9) & 3;
  const int kk = u >> 11;
  const int o = ot * 16 + (lane & 15);
  const int h0 = kk * 32 + (lane >> 4) * 8;
  const float4* src = (const float4*)(Wz + ((size_t)(ks * HID + o) * HID + h0));
  float4 f0 = src[0], f1 = src[1];
  uint4 pk;
  pk.x = bf16pair(f0.x, f0.y);
  pk.y = bf16pair(f0.z, f0.w);
  pk.z = bf16pair(f1.x, f1.y);
  pk.w = bf16pair(f1.z, f1.w);
  wfrag[u] = pk;
}

// ---------------------------------------------------------------------------
// Main: one WG (512 thr, 8 waves) per (b,c).  [R3's proven K-loop + setprio]
// Wave grid: wr = w>>1 (4 row tiles of 64), wc = w&1 (2 col tiles of 64).
// Wave tile 64x64 -> acc[4][4] = 64 AGPRs. 16 weight chunks (kk,ks) of 8KB,
// double-buffered, ONE barrier per chunk, reg-prefetched 2 chunks ahead:
//   iter c: pref=wfrag[c+2]; compute(c) from buf[c&1]; barrier; buf[c&1]=pref
//   (per-wave vmcnt wait at the ds_write, not a collective barrier drain).
// setprio(1) around the MFMA cluster: R4-vs-R8 A/B measured +5us on this
// workload (waves in a chunk are at different micro-phases).
// Register wall: acc 64 AGPR + <=64 VGPR keeps 2 WGs/CU (R7 lesson).
// Epilogue: zsum = sum_l elu(z_pre) -> global (z2 GEMV moved to k_z2; R9
// post-mortem: in-kernel fusion cost ~7us of end-of-kernel exposed latency).
// LDS: sA 64KB (256x128 bf16, 16B-slot XOR swizzle) + sW 2x8KB = 80KB.
// ---------------------------------------------------------------------------
__global__ __launch_bounds__(512, 4) void k_main(
    const float* __restrict__ x, const int* __restrict__ leaf_idx,
    const uint4* __restrict__ wfrag, float* __restrict__ zsum) {
  extern __shared__ char smem[];
  char* sA = smem;                     // 65536 B
  uint4* sW = (uint4*)(smem + 65536);  // 2 x 512 uint4 = 16384 B

  const int tid = threadIdx.x;
  const int bc = blockIdx.x;
  const int lane = tid & 63;
  const int l15 = lane & 15;
  const int hi = lane >> 4;
  const int w = tid >> 6;
  const int wr = w >> 1;  // 0..3
  const int wc = w & 1;   // 0..1

  // ---- stage data tile: 2 threads per row (gather + f32->bf16 + swizzle) ----
  {
    const int r = tid >> 1, half = tid & 1;
    const int idx = leaf_idx[bc * LL + r];
    const float4* src = (const float4*)(x + (size_t)idx * HID + half * 64);
    const int swz = (r & 15) << 4;
    char* rowp = sA + r * 256;
#pragma unroll
    for (int j = 0; j < 8; ++j) {
      float4 f0 = src[2 * j];
      float4 f1 = src[2 * j + 1];
      uint4 pk;
      pk.x = bf16pair(f0.x, f0.y);
      pk.y = bf16pair(f0.z, f0.w);
      pk.z = bf16pair(f1.x, f1.y);
      pk.w = bf16pair(f1.z, f1.w);
      *(uint4*)(rowp + (((half * 128) + j * 16) ^ swz)) = pk;
    }
  }
  // ---- stage weight chunks 0 and 1 (lane-linear, conflict-free) ----
  sW[tid] = wfrag[tid];
  sW[512 + tid] = wfrag[512 + tid];
  __syncthreads();

  f32x4 acc[4][4];
#pragma unroll
  for (int rt = 0; rt < 4; ++rt)
#pragma unroll
    for (int ot = 0; ot < 4; ++ot) acc[rt][ot] = (f32x4){0.f, 0.f, 0.f, 0.f};

  const int r0 = wr * 64;

#pragma unroll
  for (int c = 0; c < 16; ++c) {
    const int kk = c >> 2, ks = c & 3;
    uint4 pref;
    if (c < 14) pref = wfrag[(c + 2) * 512 + tid];

    const uint4* sWc = sW + (c & 1) * 512;
    const int cb = kk * 64 + hi * 16;
    uint4 af[4];
#pragma unroll
    for (int rt = 0; rt < 4; ++rt) {
      const int row = (r0 + rt * 16 + l15 + ks) & 255;
      af[rt] = *(const uint4*)(sA + row * 256 + (cb ^ ((row & 15) << 4)));
    }
    __builtin_amdgcn_s_setprio(1);
#pragma unroll
    for (int ot2 = 0; ot2 < 4; ++ot2) {
      const uint4 bw = sWc[(wc * 4 + ot2) * 64 + lane];
      const b16x8 bb = __builtin_bit_cast(b16x8, bw);
#pragma unroll
      for (int rt = 0; rt < 4; ++rt)
        acc[rt][ot2] = __builtin_amdgcn_mfma_f32_16x16x32_bf16(
            __builtin_bit_cast(b16x8, af[rt]), bb, acc[rt][ot2], 0, 0, 0);
    }
    __builtin_amdgcn_s_setprio(0);
    __syncthreads();
    if (c < 14) sW[(c & 1) * 512 + tid] = pref;
  }

  // ---- epilogue: elu + sum over this wave's 64 rows, cross-wave reduce ----
  // C/D layout (16x16x32): col = wc*64 + ot2*16 + (lane&15); row = hi*4+q
  float colsum[4];
#pragma unroll
  for (int ot2 = 0; ot2 < 4; ++ot2) {
    float s = 0.f;
#pragma unroll
    for (int rt = 0; rt < 4; ++rt)
#pragma unroll
      for (int q = 0; q < 4; ++q) s += elu(acc[rt][ot2][q]);
    s += __shfl_xor(s, 16);
    s += __shfl_xor(s, 32);
    colsum[ot2] = s;
  }
  float* sRed = (float*)sA;  // sA reads all done (last barrier)
  if (lane < 16) {
#pragma unroll
    for (int ot2 = 0; ot2 < 4; ++ot2)
      sRed[w * 64 + ot2 * 16 + lane] = colsum[ot2];
  }
  __syncthreads();
  if (tid < 128) {
    const int wc2 = tid >> 6, lc = tid & 63;
    float s = 0.f;
#pragma unroll
    for (int wrr = 0; wrr < 4; ++wrr) s += sRed[(wrr * 2 + wc2) * 64 + lc];
    zsum[bc * 128 + tid] = s;
  }
}

// ---------------------------------------------------------------------------
// z2 = elu(zsum @ Wzf^T), one block per (b,c), IN-PLACE over zsum (each
// block stages its own row in LDS before overwriting -- no cross-block dep).
// ---------------------------------------------------------------------------
__global__ __launch_bounds__(256) void k_z2(
    float* __restrict__ zsum, const float* __restrict__ Wzf) {
  __shared__ float sZ[HID];
  const int bc = blockIdx.x, tid = threadIdx.x;
  if (tid < HID) sZ[tid] = zsum[bc * HID + tid];
  __syncthreads();
  const int o = tid >> 1, sub = tid & 1;  // 2 threads per output
  const float4* wr4 = (const float4*)(Wzf + o * HID + sub * 64);
  const float4* zv4 = (const float4*)(sZ + sub * 64);
  float d0 = 0.f, d1 = 0.f;
#pragma unroll
  for (int j = 0; j < 16; j += 2) {
    float4 a0 = wr4[j], b0 = zv4[j];
    float4 a1 = wr4[j + 1], b1 = zv4[j + 1];
    d0 += a0.x * b0.x + a0.y * b0.y + a0.z * b0.z + a0.w * b0.w;
    d1 += a1.x * b1.x + a1.y * b1.y + a1.z * b1.z + a1.w * b1.w;
  }
  float d = d0 + d1;
  d += __shfl_xor(d, 1);
  if (sub == 0) zsum[bc * HID + o] = elu(d);
}

// ---------------------------------------------------------------------------
// Tail (f32, exact): s = sum_c z2[b,c,:]; p = s @ Wp^T; out = p @ Wpf^T.
// One block (256 thr) per b.
// ---------------------------------------------------------------------------
__global__ __launch_bounds__(256) void k_tail(
    const float* __restrict__ z2, const float* __restrict__ Wp,
    const float* __restrict__ Wpf, float* __restrict__ out) {
  __shared__ float sS[2][HID];
  __shared__ float sV[HID];
  __shared__ float sP[HID];
  const int tid = threadIdx.x, b = blockIdx.x;
  const int o = tid & 127, g = tid >> 7;
  float s = 0.f;
#pragma unroll
  for (int cj = 0; cj < 8; ++cj) s += z2[(size_t)(b * CC + g * 8 + cj) * HID + o];
  sS[g][o] = s;
  __syncthreads();
  if (tid < HID) sV[tid] = sS[0][tid] + sS[1][tid];
  __syncthreads();
  {
    const int o2 = tid >> 1, sub = tid & 1;
    const float4* wp4 = (const float4*)(Wp + o2 * HID + sub * 64);
    const float4* v4 = (const float4*)(sV + sub * 64);
    float d0 = 0.f, d1 = 0.f;
#pragma unroll
    for (int j = 0; j < 16; j += 2) {
      float4 a0 = wp4[j], c0 = v4[j];
      float4 a1 = wp4[j + 1], c1 = v4[j + 1];
      d0 += a0.x * c0.x + a0.y * c0.y + a0.z * c0.z + a0.w * c0.w;
      d1 += a1.x * c1.x + a1.y * c1.y + a1.z * c1.z + a1.w * c1.w;
    }
    float d = d0 + d1;
    d += __shfl_xor(d, 1);
    if (sub == 0) sP[o2] = d;
  }
  __syncthreads();
  {
    const int o2 = tid >> 1, sub = tid & 1;
    const float4* wp4 = (const float4*)(Wpf + o2 * HID + sub * 64);
    const float4* p4 = (const float4*)(sP + sub * 64);
    float d0 = 0.f, d1 = 0.f;
#pragma unroll
    for (int j = 0; j < 16; j += 2) {
      float4 a0 = wp4[j], c0 = p4[j];
      float4 a1 = wp4[j + 1], c1 = p4[j + 1];
      d0 += a0.x * c0.x + a0.y * c0.y + a0.z * c0.z + a0.w * c0.w;
      d1 += a1.x * c1.x + a1.y * c1.y + a1.z * c1.z + a1.w * c1.w;
    }
    float d = d0 + d1;
    d += __shfl_xor(d, 1);
    if (sub == 0) out[b * HID + o2] = d;
  }
}

extern "C" void kernel_launch(void* const* d_in, const int* in_sizes, int n_in,
                              void* d_out, int out_size, void* d_ws, size_t ws_size,
                              hipStream_t stream) {
  const float* x = (const float*)d_in[0];
  const int* leaf = (const int*)d_in[1];
  const float* Wz = (const float*)d_in[2];
  const float* Wzf = (const float*)d_in[3];
  const float* Wp = (const float*)d_in[4];
  const float* Wpf = (const float*)d_in[5];
  float* out = (float*)d_out;

  uint4* wfrag = (uint4*)d_ws;                   // 128 KB
  float* zsum = (float*)((char*)d_ws + 131072);  // 512 KB (z2 in-place)

  (void)hipFuncSetAttribute((const void*)k_main,
                            hipFuncAttributeMaxDynamicSharedMemorySize, 81920);

  k_prep<<<32, 256, 0, stream>>>(Wz, wfrag);
  k_main<<<1024, 512, 81920, stream>>>(x, leaf, wfrag, zsum);
  k_z2<<<1024, 256, 0, stream>>>(zsum, Wzf);
  k_tail<<<64, 256, 0, stream>>>(zsum, Wp, Wpf, out);
}

// Round 11
// 61.833 us; speedup vs baseline: 1.0544x; 1.0544x over previous
//
#include <hip/hip_runtime.h>
#include <hip/hip_bf16.h>

#define N_NODES 100000
#define HID 128
#define BB 64
#define CC 16
#define LL 256

typedef __bf16 b16x8 __attribute__((ext_vector_type(8)));
typedef float f32x4 __attribute__((ext_vector_type(4)));

__device__ __forceinline__ unsigned int bf16pair(float a, float b) {
  unsigned int ua = __float_as_uint(a), ub = __float_as_uint(b);
  ua = (ua + 0x7FFFu + ((ua >> 16) & 1u)) >> 16;
  ub = (ub + 0x7FFFu + ((ub >> 16) & 1u)) >> 16;
  return ua | (ub << 16);
}

// single-instruction packed f32->bf16 (RTNE), T12 recipe (no builtin on gfx950)
__device__ __forceinline__ unsigned int cvtpk(float a, float b) {
  unsigned int r;
  asm("v_cvt_pk_bf16_f32 %0, %1, %2" : "=v"(r) : "v"(a), "v"(b));
  return r;
}

__device__ __forceinline__ float elu(float v) {
  return v > 0.f ? v : (__expf(v) - 1.f);
}

// ---------------------------------------------------------------------------
// Prep: W_z [4][128][128] f32 -> bf16 fragment-linear layout.
// uint4 index u = ((kk*4 + ks)*8 + ot)*64 + lane
//   holds W_z[ks][o][h0..h0+7], o = ot*16 + (lane&15), h0 = kk*32 + (lane>>4)*8
// Chunk c = kk*4 + ks = 512 contiguous uint4 = 8KB.
// ---------------------------------------------------------------------------
__global__ void k_prep(const float* __restrict__ Wz, uint4* __restrict__ wfrag) {
  const int u = blockIdx.x * 256 + threadIdx.x;  // 8192 total
  const int lane = u & 63;
  const int ot = (u >> 6) & 7;
  const int ks = (u >> 9) & 3;
  const int kk = u >> 11;
  const int o = ot * 16 + (lane & 15);
  const int h0 = kk * 32 + (lane >> 4) * 8;
  const float4* src = (const float4*)(Wz + ((size_t)(ks * HID + o) * HID + h0));
  float4 f0 = src[0], f1 = src[1];
  uint4 pk;
  pk.x = bf16pair(f0.x, f0.y);
  pk.y = bf16pair(f0.z, f0.w);
  pk.z = bf16pair(f1.x, f1.y);
  pk.w = bf16pair(f1.z, f1.w);
  wfrag[u] = pk;
}

// ---------------------------------------------------------------------------
// Main: one WG (512 thr, 8 waves) per (b,c).  [R10's proven 52us kernel]
// Wave grid: wr = w>>1 (4 row tiles of 64), wc = w&1 (2 col tiles of 64).
// Wave tile 64x64 -> acc[4][4] = 64 AGPRs. 16 weight chunks (kk,ks) of 8KB,
// double-buffered, ONE barrier per chunk, reg-prefetched 2 chunks ahead:
//   iter c: pref=wfrag[c+2]; compute(c) from buf[c&1]; barrier; buf[c&1]=pref
//   (per-wave vmcnt wait at the ds_write, not a collective barrier drain).
// setprio(1) around the MFMA cluster: R4-vs-R8 A/B measured +5us here.
// Register wall: acc 64 AGPR + <=64 VGPR keeps 2 WGs/CU (R7 lesson).
// Staging conversion via v_cvt_pk_bf16_f32 (1 op/pair vs 5-op manual).
// Epilogue: zsum = sum_l elu(z_pre) -> global (z2 folded into k_tail; R10
// lesson: standalone k_z2 = 64MB Wzf L2 traffic + extra launch = 9.5us).
// LDS: sA 64KB (256x128 bf16, 16B-slot XOR swizzle) + sW 2x8KB = 80KB.
// ---------------------------------------------------------------------------
__global__ __launch_bounds__(512, 4) void k_main(
    const float* __restrict__ x, const int* __restrict__ leaf_idx,
    const uint4* __restrict__ wfrag, float* __restrict__ zsum) {
  extern __shared__ char smem[];
  char* sA = smem;                     // 65536 B
  uint4* sW = (uint4*)(smem + 65536);  // 2 x 512 uint4 = 16384 B

  const int tid = threadIdx.x;
  const int bc = blockIdx.x;
  const int lane = tid & 63;
  const int l15 = lane & 15;
  const int hi = lane >> 4;
  const int w = tid >> 6;
  const int wr = w >> 1;  // 0..3
  const int wc = w & 1;   // 0..1

  // ---- stage data tile: 2 threads per row (gather + cvt_pk + swizzle) ----
  {
    const int r = tid >> 1, half = tid & 1;
    const int idx = leaf_idx[bc * LL + r];
    const float4* src = (const float4*)(x + (size_t)idx * HID + half * 64);
    const int swz = (r & 15) << 4;
    char* rowp = sA + r * 256;
#pragma unroll
    for (int j = 0; j < 8; ++j) {
      float4 f0 = src[2 * j];
      float4 f1 = src[2 * j + 1];
      uint4 pk;
      pk.x = cvtpk(f0.x, f0.y);
      pk.y = cvtpk(f0.z, f0.w);
      pk.z = cvtpk(f1.x, f1.y);
      pk.w = cvtpk(f1.z, f1.w);
      *(uint4*)(rowp + (((half * 128) + j * 16) ^ swz)) = pk;
    }
  }
  // ---- stage weight chunks 0 and 1 (lane-linear, conflict-free) ----
  sW[tid] = wfrag[tid];
  sW[512 + tid] = wfrag[512 + tid];
  __syncthreads();

  f32x4 acc[4][4];
#pragma unroll
  for (int rt = 0; rt < 4; ++rt)
#pragma unroll
    for (int ot = 0; ot < 4; ++ot) acc[rt][ot] = (f32x4){0.f, 0.f, 0.f, 0.f};

  const int r0 = wr * 64;

#pragma unroll
  for (int c = 0; c < 16; ++c) {
    const int kk = c >> 2, ks = c & 3;
    uint4 pref;
    if (c < 14) pref = wfrag[(c + 2) * 512 + tid];

    const uint4* sWc = sW + (c & 1) * 512;
    const int cb = kk * 64 + hi * 16;
    uint4 af[4];
#pragma unroll
    for (int rt = 0; rt < 4; ++rt) {
      const int row = (r0 + rt * 16 + l15 + ks) & 255;
      af[rt] = *(const uint4*)(sA + row * 256 + (cb ^ ((row & 15) << 4)));
    }
    __builtin_amdgcn_s_setprio(1);
#pragma unroll
    for (int ot2 = 0; ot2 < 4; ++ot2) {
      const uint4 bw = sWc[(wc * 4 + ot2) * 64 + lane];
      const b16x8 bb = __builtin_bit_cast(b16x8, bw);
#pragma unroll
      for (int rt = 0; rt < 4; ++rt)
        acc[rt][ot2] = __builtin_amdgcn_mfma_f32_16x16x32_bf16(
            __builtin_bit_cast(b16x8, af[rt]), bb, acc[rt][ot2], 0, 0, 0);
    }
    __builtin_amdgcn_s_setprio(0);
    __syncthreads();
    if (c < 14) sW[(c & 1) * 512 + tid] = pref;
  }

  // ---- epilogue: elu + sum over this wave's 64 rows, cross-wave reduce ----
  // C/D layout (16x16x32): col = wc*64 + ot2*16 + (lane&15); row = hi*4+q
  float colsum[4];
#pragma unroll
  for (int ot2 = 0; ot2 < 4; ++ot2) {
    float s = 0.f;
#pragma unroll
    for (int rt = 0; rt < 4; ++rt)
#pragma unroll
      for (int q = 0; q < 4; ++q) s += elu(acc[rt][ot2][q]);
    s += __shfl_xor(s, 16);
    s += __shfl_xor(s, 32);
    colsum[ot2] = s;
  }
  float* sRed = (float*)sA;  // sA reads all done (last barrier)
  if (lane < 16) {
#pragma unroll
    for (int ot2 = 0; ot2 < 4; ++ot2)
      sRed[w * 64 + ot2 * 16 + lane] = colsum[ot2];
  }
  __syncthreads();
  if (tid < 128) {
    const int wc2 = tid >> 6, lc = tid & 63;
    float s = 0.f;
#pragma unroll
    for (int wrr = 0; wrr < 4; ++wrr) s += sRed[(wrr * 2 + wc2) * 64 + lc];
    zsum[bc * 128 + tid] = s;
  }
}

// ---------------------------------------------------------------------------
// Tail (f32, exact), one block (512 thr) per b:
//   z2[c] = elu(zsum[b,c] @ Wzf^T); s = sum_c z2[c]; p = s @ Wp^T;
//   out = p @ Wpf^T.
// Wzf row is hoisted: each thread reads its row ONCE (j-outer loop) --
// R3/R10 lesson: per-c re-reads / 1024-block z2 kernels cost 9-30us in
// Wzf L2 traffic; here it's 64 blocks x 256KB (L1-dedup'd to 64KB).
// ---------------------------------------------------------------------------
__global__ __launch_bounds__(512) void k_tail(
    const float* __restrict__ zsum, const float* __restrict__ Wzf,
    const float* __restrict__ Wp, const float* __restrict__ Wpf,
    float* __restrict__ out) {
  __shared__ float sZ[CC * HID];  // 8KB
  __shared__ float sS[4][HID];
  __shared__ float sV[HID];
  __shared__ float sP[HID];
  const int tid = threadIdx.x, b = blockIdx.x;
#pragma unroll
  for (int j = 0; j < 4; ++j)
    sZ[tid + j * 512] = zsum[(size_t)b * (CC * HID) + tid + j * 512];
  __syncthreads();

  // z2 + c-sum: o = tid&127, g = tid>>7 owns c = g*4..g*4+3
  {
    const int o = tid & 127, g = tid >> 7;
    const float4* wr4 = (const float4*)(Wzf + o * HID);
    float d0 = 0.f, d1 = 0.f, d2 = 0.f, d3 = 0.f;
#pragma unroll
    for (int j = 0; j < 32; ++j) {
      const float4 wv = wr4[j];
      const float4 z0 = *(const float4*)(sZ + (g * 4 + 0) * HID + j * 4);
      const float4 z1 = *(const float4*)(sZ + (g * 4 + 1) * HID + j * 4);
      const float4 z2v = *(const float4*)(sZ + (g * 4 + 2) * HID + j * 4);
      const float4 z3 = *(const float4*)(sZ + (g * 4 + 3) * HID + j * 4);
      d0 += wv.x * z0.x + wv.y * z0.y + wv.z * z0.z + wv.w * z0.w;
      d1 += wv.x * z1.x + wv.y * z1.y + wv.z * z1.z + wv.w * z1.w;
      d2 += wv.x * z2v.x + wv.y * z2v.y + wv.z * z2v.z + wv.w * z2v.w;
      d3 += wv.x * z3.x + wv.y * z3.y + wv.z * z3.z + wv.w * z3.w;
    }
    sS[g][o] = elu(d0) + elu(d1) + elu(d2) + elu(d3);
  }
  __syncthreads();
  if (tid < HID) sV[tid] = sS[0][tid] + sS[1][tid] + sS[2][tid] + sS[3][tid];
  __syncthreads();

  // p = sV @ Wp^T : 4 threads per output
  {
    const int o2 = tid >> 2, sub = tid & 3;
    const float4* wp4 = (const float4*)(Wp + o2 * HID + sub * 32);
    const float4* v4 = (const float4*)(sV + sub * 32);
    float d0 = 0.f, d1 = 0.f;
#pragma unroll
    for (int j = 0; j < 8; j += 2) {
      float4 a0 = wp4[j], c0 = v4[j];
      float4 a1 = wp4[j + 1], c1 = v4[j + 1];
      d0 += a0.x * c0.x + a0.y * c0.y + a0.z * c0.z + a0.w * c0.w;
      d1 += a1.x * c1.x + a1.y * c1.y + a1.z * c1.z + a1.w * c1.w;
    }
    float d = d0 + d1;
    d += __shfl_xor(d, 1);
    d += __shfl_xor(d, 2);
    if (sub == 0) sP[o2] = d;
  }
  __syncthreads();

  // out = sP @ Wpf^T : 4 threads per output
  {
    const int o2 = tid >> 2, sub = tid & 3;
    const float4* wp4 = (const float4*)(Wpf + o2 * HID + sub * 32);
    const float4* p4 = (const float4*)(sP + sub * 32);
    float d0 = 0.f, d1 = 0.f;
#pragma unroll
    for (int j = 0; j < 8; j += 2) {
      float4 a0 = wp4[j], c0 = p4[j];
      float4 a1 = wp4[j + 1], c1 = p4[j + 1];
      d0 += a0.x * c0.x + a0.y * c0.y + a0.z * c0.z + a0.w * c0.w;
      d1 += a1.x * c1.x + a1.y * c1.y + a1.z * c1.z + a1.w * c1.w;
    }
    float d = d0 + d1;
    d += __shfl_xor(d, 1);
    d += __shfl_xor(d, 2);
    if (sub == 0) out[b * HID + o2] = d;
  }
}

extern "C" void kernel_launch(void* const* d_in, const int* in_sizes, int n_in,
                              void* d_out, int out_size, void* d_ws, size_t ws_size,
                              hipStream_t stream) {
  const float* x = (const float*)d_in[0];
  const int* leaf = (const int*)d_in[1];
  const float* Wz = (const float*)d_in[2];
  const float* Wzf = (const float*)d_in[3];
  const float* Wp = (const float*)d_in[4];
  const float* Wpf = (const float*)d_in[5];
  float* out = (float*)d_out;

  uint4* wfrag = (uint4*)d_ws;                   // 128 KB
  float* zsum = (float*)((char*)d_ws + 131072);  // 512 KB

  (void)hipFuncSetAttribute((const void*)k_main,
                            hipFuncAttributeMaxDynamicSharedMemorySize, 81920);

  k_prep<<<32, 256, 0, stream>>>(Wz, wfrag);
  k_main<<<1024, 512, 81920, stream>>>(x, leaf, wfrag, zsum);
  k_tail<<<64, 512, 0, stream>>>(zsum, Wzf, Wp, Wpf, out);
}